// Round 4
// baseline (254.391 us; speedup 1.0000x reference)
//
#include <hip/hip_runtime.h>
#include <hip/hip_bf16.h>

// Problem constants (CeptaBlock): B=4,T=2048,D=2048,P=512,K=16,ALPHA=4,R=32
#define B_ 4
#define T_ 2048
#define D_ 2048
#define P_ 512
#define K_ 16
#define ALPHA_ 4
#define R_ 32
#define NE_ 409        // int(0.8*512) -> excitatory count
#define EPS_ 1e-6f
#define G_ 4           // tokens per block

typedef unsigned short u16;
typedef unsigned int u32;

__device__ __forceinline__ float sigmoidf_(float x) {
  return 1.0f / (1.0f + __expf(-x));
}
__device__ __forceinline__ float bfb2f(u32 u) {
  return __uint_as_float(u << 16);
}
__device__ __forceinline__ u16 f2bfb(float f) {
  __hip_bfloat16 h = __float2bfloat16(f);
  return *reinterpret_cast<u16*>(&h);
}

// ---------------- K1: rmsnorm1 + gather + perceptron + z/lam, G_ tokens/block ----------------
__global__ __launch_bounds__(256, 4) void k_phase1(
    const float* __restrict__ x, const float* __restrict__ g1,
    const int* __restrict__ idx, const float* __restrict__ wg,
    const float* __restrict__ U, const float* __restrict__ Wgt,
    const float* __restrict__ bg, const float* __restrict__ Wp,
    u16* __restrict__ f_ssm, float* __restrict__ z, float* __restrict__ lam) {
  __shared__ u16 h1[G_][D_];          // 16 KB bf16 normalized activations
  __shared__ u32 ft[G_][P_];          // 8 KB packed (f | t<<16) bf16
  __shared__ float red[G_][4];
  __shared__ float zp[G_][R_][4];     // 2 KB
  __shared__ float lp[G_][R_][4];     // 2 KB

  int tid = threadIdx.x;
  int token0 = blockIdx.x * G_;
  int b = token0 >> 11;
  int t0 = token0 & (T_ - 1);
  int p0 = 2 * tid, p1 = p0 + 1;

  // ---- front-load: x (4 tokens), g1, Wp (for local wq) ----
  float xv[G_][8];
#pragma unroll
  for (int tok = 0; tok < G_; tok++) {
    const float4* xp = reinterpret_cast<const float4*>(x + (size_t)(token0 + tok) * D_ + tid * 8);
    *reinterpret_cast<float4*>(&xv[tok][0]) = xp[0];
    *reinterpret_cast<float4*>(&xv[tok][4]) = xp[1];
  }
  float gv[8];
  {
    const float4* gp = reinterpret_cast<const float4*>(g1 + tid * 8);
    *reinterpret_cast<float4*>(&gv[0]) = gp[0];
    *reinterpret_cast<float4*>(&gv[4]) = gp[1];
  }
  // local quant scalars wq for p0,p1 (register-local, no barrier needed)
  float wq0, wq1;
  {
    const float4* w0 = reinterpret_cast<const float4*>(Wp + p0 * K_);
    const float4* w1 = reinterpret_cast<const float4*>(Wp + p1 * K_);
    float a0 = 0, a1 = 0;
#pragma unroll
    for (int q = 0; q < 4; q++) {
      float4 v0 = w0[q], v1 = w1[q];
      a0 += fabsf(v0.x) + fabsf(v0.y) + fabsf(v0.z) + fabsf(v0.w);
      a1 += fabsf(v1.x) + fabsf(v1.y) + fabsf(v1.z) + fabsf(v1.w);
    }
    wq0 = ((p0 < NE_) ? 1.0f : -1.0f) * a0 * (1.0f / K_);
    wq1 = ((p1 < NE_) ? 1.0f : -1.0f) * a1 * (1.0f / K_);
  }

  // ---- rmsnorm sums ----
#pragma unroll
  for (int tok = 0; tok < G_; tok++) {
    float s = 0;
#pragma unroll
    for (int i = 0; i < 8; i++) s += xv[tok][i] * xv[tok][i];
#pragma unroll
    for (int off = 32; off; off >>= 1) s += __shfl_down(s, off);
    if ((tid & 63) == 0) red[tok][tid >> 6] = s;
  }
  __syncthreads();
#pragma unroll
  for (int tok = 0; tok < G_; tok++) {
    float inv = rsqrtf((red[tok][0] + red[tok][1] + red[tok][2] + red[tok][3]) * (1.0f / D_) + EPS_);
    u16 tmp[8];
#pragma unroll
    for (int i = 0; i < 8; i++) tmp[i] = f2bfb(xv[tok][i] * inv * gv[i]);
    *reinterpret_cast<uint4*>(&h1[tok][tid * 8]) = *reinterpret_cast<const uint4*>(tmp);
  }

  // gather weights (issued while barrier drains)
  union { int4 v[4]; int s[16]; } iu0, iu1;
  union { float4 v[4]; float s[16]; } wu0, wu1;
  {
    const int4* ip0 = reinterpret_cast<const int4*>(idx + p0 * K_);
    const int4* ip1 = reinterpret_cast<const int4*>(idx + p1 * K_);
    const float4* wp0 = reinterpret_cast<const float4*>(wg + p0 * K_);
    const float4* wp1 = reinterpret_cast<const float4*>(wg + p1 * K_);
#pragma unroll
    for (int q = 0; q < 4; q++) { iu0.v[q] = ip0[q]; iu1.v[q] = ip1[q]; wu0.v[q] = wp0[q]; wu1.v[q] = wp1[q]; }
  }
  __syncthreads();

  // ---- perceptron: p0,p1 per thread, token-inner ----
#pragma unroll
  for (int tok = 0; tok < G_; tok++) {
    float a0 = 0, a1 = 0;
#pragma unroll
    for (int k = 0; k < K_; k++) {
      a0 += bfb2f(h1[tok][iu0.s[k]]) * wu0.s[k];
      a1 += bfb2f(h1[tok][iu1.s[k]]) * wu1.s[k];
    }
    float u0 = wq0 * a0, u1 = wq1 * a1;
    float f0 = sigmoidf_(u0), f1 = sigmoidf_(u1);
    u32 pk0 = (u32)f2bfb(f0) | ((u32)f2bfb(f0 * u0) << 16);
    u32 pk1 = (u32)f2bfb(f1) | ((u32)f2bfb(f1 * u1) << 16);
    *reinterpret_cast<uint2*>(&ft[tok][p0]) = make_uint2(pk0, pk1);
    *reinterpret_cast<u32*>(f_ssm + (size_t)(token0 + tok) * P_ + p0) =
        (u32)f2bfb(f0) | ((u32)f2bfb(f1) << 16);
  }
  __syncthreads();

  // ---- z = t@U, lam_pre = f@Wgate ----
  int r = tid & 31, g = tid >> 5;  // 32 r x 8 p-groups of 64
  float zs[G_], ls[G_];
#pragma unroll
  for (int tok = 0; tok < G_; tok++) { zs[tok] = 0; ls[tok] = 0; }
  int pbase = g * 64;
#pragma unroll 8
  for (int pp = 0; pp < 64; pp++) {
    int p = pbase + pp;
    float uu = U[p * R_ + r];
    float ww = Wgt[p * R_ + r];
#pragma unroll
    for (int tok = 0; tok < G_; tok++) {
      u32 v = ft[tok][p];
      zs[tok] += bfb2f(v >> 16) * uu;
      ls[tok] += bfb2f(v & 0xffffu) * ww;
    }
  }
#pragma unroll
  for (int tok = 0; tok < G_; tok++) {
    zs[tok] += __shfl_down(zs[tok], 32);
    ls[tok] += __shfl_down(ls[tok], 32);
  }
  int wid = tid >> 6;
  if ((tid & 63) < 32) {
#pragma unroll
    for (int tok = 0; tok < G_; tok++) {
      zp[tok][r][wid] = zs[tok];
      lp[tok][r][wid] = ls[tok];
    }
  }
  __syncthreads();
  if (tid < R_) {
    float bgr = bg[tid];
    float z4[G_], l4[G_];
#pragma unroll
    for (int tok = 0; tok < G_; tok++) {
      float zz = zp[tok][tid][0] + zp[tok][tid][1] + zp[tok][tid][2] + zp[tok][tid][3];
      float ll = lp[tok][tid][0] + lp[tok][tid][1] + lp[tok][tid][2] + lp[tok][tid][3];
      z4[tok] = zz;
      l4[tok] = sigmoidf_(ll + bgr);
    }
    size_t o = ((size_t)(b * R_ + tid)) * T_ + t0;
    *reinterpret_cast<float4*>(&z[o]) = *reinterpret_cast<const float4*>(z4);
    *reinterpret_cast<float4*>(&lam[o]) = *reinterpret_cast<const float4*>(l4);
  }
}

// ---------------- K2: parallel linear scan over T (one wave per (b,r)) ----------------
__global__ __launch_bounds__(64) void k_scan(
    const float* __restrict__ z, const float* __restrict__ lam,
    const float* __restrict__ state, float* __restrict__ S,
    float* __restrict__ out_state) {
  int br = blockIdx.x;     // b*R + r   (128 total)
  int lane = threadIdx.x;  // 64 lanes, 32 timesteps each
  const float* zr = z + (size_t)br * T_ + lane * 32;
  const float* lr = lam + (size_t)br * T_ + lane * 32;
  float zb[32], lb[32];
#pragma unroll
  for (int i = 0; i < 32; i += 4) {
    *reinterpret_cast<float4*>(&zb[i]) = *reinterpret_cast<const float4*>(&zr[i]);
    *reinterpret_cast<float4*>(&lb[i]) = *reinterpret_cast<const float4*>(&lr[i]);
  }
  float A = 1.0f, Z = 0.0f;
#pragma unroll
  for (int i = 0; i < 32; i++) { Z = lb[i] * Z + zb[i]; A *= lb[i]; }
  for (int off = 1; off < 64; off <<= 1) {
    float Ap = __shfl_up(A, off);
    float Zp = __shfl_up(Z, off);
    if (lane >= off) { Z = A * Zp + Z; A = A * Ap; }
  }
  float s0 = state[br];
  float Ae = __shfl_up(A, 1);
  float Ze = __shfl_up(Z, 1);
  float s = (lane == 0) ? s0 : (Ae * s0 + Ze);
  float sb[32];
#pragma unroll
  for (int i = 0; i < 32; i++) { s = lb[i] * s + zb[i]; sb[i] = s; }
  float* Sr = S + (size_t)br * T_ + lane * 32;
#pragma unroll
  for (int i = 0; i < 32; i += 4)
    *reinterpret_cast<float4*>(&Sr[i]) = *reinterpret_cast<const float4*>(&sb[i]);
  if (lane == 63) out_state[br] = s;  // new_state
}

// ---------------- K3: tilde=S@V, y_ssm, x_after, rmsnorm2, MLP, out ----------------
__global__ __launch_bounds__(256, 4) void k_phase3(
    const float* __restrict__ x, const float* __restrict__ g2,
    const int* __restrict__ idx, const float* __restrict__ wg,
    const float* __restrict__ V, const float* __restrict__ S,
    const u16* __restrict__ f_ssm, const float* __restrict__ Wo_s,
    const float* __restrict__ Wp_m, const float* __restrict__ Wo_m,
    float* __restrict__ out) {
  __shared__ float Sl[G_][R_];
  __shared__ u16 h2[G_][D_];          // 16 KB
  __shared__ float red[G_][4];

  int tid = threadIdx.x;
  int token0 = blockIdx.x * G_;
  int b = token0 >> 11;
  int t0 = token0 & (T_ - 1);
  int p0 = 2 * tid, p1 = p0 + 1;

  if (tid < G_ * R_) {
    int tok = tid >> 5, r = tid & 31;
    Sl[tok][r] = S[((size_t)(b * R_ + r)) * T_ + t0 + tok];
  }

  // ---- front-load: x (4 tokens), f pairs, local scalars, g2 ----
  float xa[G_][8];
#pragma unroll
  for (int tok = 0; tok < G_; tok++) {
    const float4* xp = reinterpret_cast<const float4*>(x + (size_t)(token0 + tok) * D_ + tid * 8);
    *reinterpret_cast<float4*>(&xa[tok][0]) = xp[0];
    *reinterpret_cast<float4*>(&xa[tok][4]) = xp[1];
  }
  u32 fpair[G_];
#pragma unroll
  for (int tok = 0; tok < G_; tok++)
    fpair[tok] = *reinterpret_cast<const u32*>(f_ssm + (size_t)(token0 + tok) * P_ + p0);

  float sgn0 = (p0 < NE_) ? 1.0f : -1.0f;
  float sgn1 = (p1 < NE_) ? 1.0f : -1.0f;
  float fo_s0, fo_s1, fo_m0, fo_m1, wq_m0, wq_m1;
  {
    float4 a = *reinterpret_cast<const float4*>(Wo_s + p0 * ALPHA_);
    float4 c = *reinterpret_cast<const float4*>(Wo_s + p1 * ALPHA_);
    fo_s0 = sgn0 * (fabsf(a.x) + fabsf(a.y) + fabsf(a.z) + fabsf(a.w)) * (1.0f / ALPHA_);
    fo_s1 = sgn1 * (fabsf(c.x) + fabsf(c.y) + fabsf(c.z) + fabsf(c.w)) * (1.0f / ALPHA_);
    float4 e = *reinterpret_cast<const float4*>(Wo_m + p0 * ALPHA_);
    float4 g = *reinterpret_cast<const float4*>(Wo_m + p1 * ALPHA_);
    fo_m0 = sgn0 * (fabsf(e.x) + fabsf(e.y) + fabsf(e.z) + fabsf(e.w)) * (1.0f / ALPHA_);
    fo_m1 = sgn1 * (fabsf(g.x) + fabsf(g.y) + fabsf(g.z) + fabsf(g.w)) * (1.0f / ALPHA_);
    const float4* w0 = reinterpret_cast<const float4*>(Wp_m + p0 * K_);
    const float4* w1 = reinterpret_cast<const float4*>(Wp_m + p1 * K_);
    float a0 = 0, a1 = 0;
#pragma unroll
    for (int q = 0; q < 4; q++) {
      float4 v0 = w0[q], v1 = w1[q];
      a0 += fabsf(v0.x) + fabsf(v0.y) + fabsf(v0.z) + fabsf(v0.w);
      a1 += fabsf(v1.x) + fabsf(v1.y) + fabsf(v1.z) + fabsf(v1.w);
    }
    wq_m0 = sgn0 * a0 * (1.0f / K_);
    wq_m1 = sgn1 * a1 * (1.0f / K_);
  }
  float gv[8];
  {
    const float4* gp = reinterpret_cast<const float4*>(g2 + tid * 8);
    *reinterpret_cast<float4*>(&gv[0]) = gp[0];
    *reinterpret_cast<float4*>(&gv[4]) = gp[1];
  }
  __syncthreads();  // Sl ready

  // ---- tilde = S @ V ----
  float til0[G_], til1[G_];
#pragma unroll
  for (int tok = 0; tok < G_; tok++) { til0[tok] = 0; til1[tok] = 0; }
#pragma unroll 8
  for (int r = 0; r < R_; r++) {
    float2 vv = *reinterpret_cast<const float2*>(V + r * P_ + p0);
#pragma unroll
    for (int tok = 0; tok < G_; tok++) {
      float s = Sl[tok][r];
      til0[tok] += s * vv.x;
      til1[tok] += s * vv.y;
    }
  }

  // ---- xa = x + y_ssm, rmsnorm2 ----
#pragma unroll
  for (int tok = 0; tok < G_; tok++) {
    float f0 = bfb2f(fpair[tok] & 0xffffu);
    float f1 = bfb2f(fpair[tok] >> 16);
    float val0 = f0 * til0[tok] * fo_s0;
    float val1 = f1 * til1[tok] * fo_s1;
    float ss = 0;
#pragma unroll
    for (int a = 0; a < 4; a++) {
      xa[tok][a] += val0;
      xa[tok][4 + a] += val1;
      ss += xa[tok][a] * xa[tok][a] + xa[tok][4 + a] * xa[tok][4 + a];
    }
#pragma unroll
    for (int off = 32; off; off >>= 1) ss += __shfl_down(ss, off);
    if ((tid & 63) == 0) red[tok][tid >> 6] = ss;
  }
  __syncthreads();
#pragma unroll
  for (int tok = 0; tok < G_; tok++) {
    float inv = rsqrtf((red[tok][0] + red[tok][1] + red[tok][2] + red[tok][3]) * (1.0f / D_) + EPS_);
    u16 tmp[8];
#pragma unroll
    for (int i = 0; i < 8; i++) tmp[i] = f2bfb(xa[tok][i] * inv * gv[i]);
    *reinterpret_cast<uint4*>(&h2[tok][tid * 8]) = *reinterpret_cast<const uint4*>(tmp);
  }
  __syncthreads();

  // ---- MLP gather (two passes: p0 then p1, accumulate into xa) ----
#pragma unroll
  for (int j = 0; j < 2; j++) {
    int p = p0 + j;
    union { int4 v[4]; int s[16]; } iu;
    union { float4 v[4]; float s[16]; } wu;
    const int4* ip = reinterpret_cast<const int4*>(idx + p * K_);
    const float4* wp = reinterpret_cast<const float4*>(wg + p * K_);
#pragma unroll
    for (int q = 0; q < 4; q++) { iu.v[q] = ip[q]; wu.v[q] = wp[q]; }
    float wqm = j ? wq_m1 : wq_m0;
    float fom = j ? fo_m1 : fo_m0;
#pragma unroll
    for (int tok = 0; tok < G_; tok++) {
      float acc = 0;
#pragma unroll
      for (int k = 0; k < K_; k++) acc += bfb2f(h2[tok][iu.s[k]]) * wu.s[k];
      float u = wqm * acc;
      float f = sigmoidf_(u);
      float val = f * u * fom;
#pragma unroll
      for (int a = 0; a < 4; a++) xa[tok][j * 4 + a] += val;
    }
  }
#pragma unroll
  for (int tok = 0; tok < G_; tok++) {
    float4* op = reinterpret_cast<float4*>(out + (size_t)(token0 + tok) * D_ + tid * 8);
    op[0] = *reinterpret_cast<const float4*>(&xa[tok][0]);
    op[1] = *reinterpret_cast<const float4*>(&xa[tok][4]);
  }
}

// ---------------- host ----------------
extern "C" void kernel_launch(void* const* d_in, const int* in_sizes, int n_in,
                              void* d_out, int out_size, void* d_ws, size_t ws_size,
                              hipStream_t stream) {
  const float* x     = (const float*)d_in[0];
  const float* state = (const float*)d_in[1];
  const float* g1    = (const float*)d_in[2];
  const float* g2    = (const float*)d_in[3];
  const int*   idx_s = (const int*)d_in[4];
  const float* wg_s  = (const float*)d_in[5];
  const int*   idx_m = (const int*)d_in[6];
  const float* wg_m  = (const float*)d_in[7];
  const float* Wp_s  = (const float*)d_in[8];
  const float* Wo_s  = (const float*)d_in[9];
  const float* Wp_m  = (const float*)d_in[10];
  const float* Wo_m  = (const float*)d_in[11];
  const float* U     = (const float*)d_in[12];
  const float* V     = (const float*)d_in[13];
  const float* Wgt   = (const float*)d_in[14];
  const float* bg    = (const float*)d_in[15];
  float* out = (float*)d_out;

  char* ws = (char*)d_ws;
  u16* f_ssm = (u16*)ws;                                               // B*T*P bf16 = 8 MB
  size_t off = (size_t)B_ * T_ * P_ * 2;
  float* z   = (float*)(ws + off); off += (size_t)B_ * R_ * T_ * 4;    // 1 MB
  float* lam = (float*)(ws + off); off += (size_t)B_ * R_ * T_ * 4;    // 1 MB
  float* S   = (float*)(ws + off);                                     // 1 MB

  hipLaunchKernelGGL(k_phase1, dim3(B_ * T_ / G_), dim3(256), 0, stream,
                     x, g1, idx_s, wg_s, U, Wgt, bg, Wp_s, f_ssm, z, lam);
  hipLaunchKernelGGL(k_scan, dim3(B_ * R_), dim3(64), 0, stream,
                     z, lam, state, S, out + (size_t)B_ * T_ * D_);
  hipLaunchKernelGGL(k_phase3, dim3(B_ * T_ / G_), dim3(256), 0, stream,
                     x, g2, idx_m, wg_m, V, S, f_ssm, Wo_s, Wp_m, Wo_m, out);
}

// Round 5
// 228.733 us; speedup vs baseline: 1.1122x; 1.1122x over previous
//
#include <hip/hip_runtime.h>
#include <hip/hip_bf16.h>

// Problem constants (CeptaBlock): B=4,T=2048,D=2048,P=512,K=16,ALPHA=4,R=32
#define B_ 4
#define T_ 2048
#define D_ 2048
#define P_ 512
#define K_ 16
#define ALPHA_ 4
#define R_ 32
#define NE_ 409        // int(0.8*512) -> excitatory count
#define EPS_ 1e-6f
#define G_ 4           // tokens per block (phase1a/phase3b)
#define TK_ 16         // tokens per block (zlam/tilde)

typedef unsigned short u16;
typedef unsigned int u32;

__device__ __forceinline__ float sigmoidf_(float x) {
  return 1.0f / (1.0f + __expf(-x));
}
__device__ __forceinline__ float bfb2f(u32 u) {
  return __uint_as_float(u << 16);
}
__device__ __forceinline__ u16 f2bfb(float f) {
  __hip_bfloat16 h = __float2bfloat16(f);
  return *reinterpret_cast<u16*>(&h);
}

// ---------------- K1a: rmsnorm1 + gather + perceptron -> packed (f|t<<16) ----------------
__global__ __launch_bounds__(256) void k_phase1a(
    const float* __restrict__ x, const float* __restrict__ g1,
    const int* __restrict__ idx, const float* __restrict__ wg,
    const float* __restrict__ Wp, u32* __restrict__ ftg) {
  __shared__ u16 h1[G_][D_];          // 16 KB bf16 normalized activations
  __shared__ float red[G_][4];

  int tid = threadIdx.x;
  int token0 = blockIdx.x * G_;

  // rmsnorm for G_ tokens
  float gv[8];
  {
    const float4* gp = reinterpret_cast<const float4*>(g1 + tid * 8);
    *reinterpret_cast<float4*>(&gv[0]) = gp[0];
    *reinterpret_cast<float4*>(&gv[4]) = gp[1];
  }
  float xv[G_][8];
  float ssv[G_];
#pragma unroll
  for (int tok = 0; tok < G_; tok++) {
    const float4* xp = reinterpret_cast<const float4*>(x + (size_t)(token0 + tok) * D_ + tid * 8);
    *reinterpret_cast<float4*>(&xv[tok][0]) = xp[0];
    *reinterpret_cast<float4*>(&xv[tok][4]) = xp[1];
    float ss = 0;
#pragma unroll
    for (int i = 0; i < 8; i++) ss += xv[tok][i] * xv[tok][i];
    ssv[tok] = ss;
  }
#pragma unroll
  for (int tok = 0; tok < G_; tok++) {
    float s = ssv[tok];
#pragma unroll
    for (int off = 32; off; off >>= 1) s += __shfl_down(s, off);
    if ((tid & 63) == 0) red[tok][tid >> 6] = s;
  }
  __syncthreads();
#pragma unroll
  for (int tok = 0; tok < G_; tok++) {
    float inv = rsqrtf((red[tok][0] + red[tok][1] + red[tok][2] + red[tok][3]) * (1.0f / D_) + EPS_);
    u16 tmp[8];
#pragma unroll
    for (int i = 0; i < 8; i++) tmp[i] = f2bfb(xv[tok][i] * inv * gv[i]);
    *reinterpret_cast<uint4*>(&h1[tok][tid * 8]) = *reinterpret_cast<const uint4*>(tmp);
  }
  __syncthreads();

  // perceptron: 2 p per thread (p = tid, tid+256), weights cached, token-inner
#pragma unroll
  for (int j = 0; j < 2; j++) {
    int p = tid + j * 256;
    union { int4 v[4]; int s[16]; } iu;
    const int4* ip = reinterpret_cast<const int4*>(idx + p * K_);
    iu.v[0] = ip[0]; iu.v[1] = ip[1]; iu.v[2] = ip[2]; iu.v[3] = ip[3];
    union { float4 v[4]; float s[16]; } wu;
    const float4* wp = reinterpret_cast<const float4*>(wg + p * K_);
    wu.v[0] = wp[0]; wu.v[1] = wp[1]; wu.v[2] = wp[2]; wu.v[3] = wp[3];
    // local quant scale wq_p = sign * mean|Wp[p,:]|
    float wqp;
    {
      const float4* w0 = reinterpret_cast<const float4*>(Wp + p * K_);
      float a0 = 0;
#pragma unroll
      for (int q = 0; q < 4; q++) {
        float4 v0 = w0[q];
        a0 += fabsf(v0.x) + fabsf(v0.y) + fabsf(v0.z) + fabsf(v0.w);
      }
      wqp = ((p < NE_) ? 1.0f : -1.0f) * a0 * (1.0f / K_);
    }
#pragma unroll
    for (int tok = 0; tok < G_; tok++) {
      float acc = 0;
#pragma unroll
      for (int k = 0; k < K_; k++) acc += bfb2f(h1[tok][iu.s[k]]) * wu.s[k];
      float u = wqp * acc;
      float f = sigmoidf_(u);
      ftg[(size_t)(token0 + tok) * P_ + p] =
          (u32)f2bfb(f) | ((u32)f2bfb(f * u) << 16);
    }
  }
}

// ---------------- K_zlam: z = t@U, lam = sigmoid(f@Wgate + bg), 16 tokens/block ----------------
__global__ __launch_bounds__(256) void k_zlam(
    const u32* __restrict__ ftg, const float* __restrict__ U,
    const float* __restrict__ Wgt, const float* __restrict__ bg,
    float* __restrict__ z, float* __restrict__ lam) {
  __shared__ float U_lds[128 * R_];    // 16 KB per chunk
  __shared__ float W_lds[128 * R_];    // 16 KB
  __shared__ u32 ft_lds[TK_][128];     // 8 KB

  int tid = threadIdx.x;
  int token0 = blockIdx.x * TK_;
  int b = token0 >> 11;
  int tbase = token0 & (T_ - 1);
  int r = tid & 31, tq = tid >> 5;     // 32 r x 8 token-pairs

  float z0 = 0, z1 = 0, l0 = 0, l1 = 0;

  for (int c = 0; c < P_ / 128; c++) {
    // stage U/Wgt chunk (contiguous 16 KB each) + ft tile
    const float4* Ug = reinterpret_cast<const float4*>(U + c * 128 * R_);
    const float4* Wg = reinterpret_cast<const float4*>(Wgt + c * 128 * R_);
#pragma unroll
    for (int k = 0; k < 4; k++) {
      int vidx = k * 256 + tid;
      reinterpret_cast<float4*>(U_lds)[vidx] = Ug[vidx];
      reinterpret_cast<float4*>(W_lds)[vidx] = Wg[vidx];
    }
#pragma unroll
    for (int k = 0; k < 2; k++) {
      int vidx = k * 256 + tid;
      int row = vidx >> 5, c4 = vidx & 31;
      reinterpret_cast<uint4*>(&ft_lds[row][0])[c4] =
          *reinterpret_cast<const uint4*>(ftg + (size_t)(token0 + row) * P_ + c * 128 + c4 * 4);
    }
    __syncthreads();
#pragma unroll 8
    for (int pp = 0; pp < 128; pp++) {
      float uu = U_lds[pp * R_ + r];
      float ww = W_lds[pp * R_ + r];
      u32 v0 = ft_lds[2 * tq][pp];
      u32 v1 = ft_lds[2 * tq + 1][pp];
      z0 += bfb2f(v0 >> 16) * uu;
      l0 += bfb2f(v0 & 0xffffu) * ww;
      z1 += bfb2f(v1 >> 16) * uu;
      l1 += bfb2f(v1 & 0xffffu) * ww;
    }
    __syncthreads();
  }
  float bgr = bg[r];
  size_t o = ((size_t)(b * R_ + r)) * T_ + tbase + 2 * tq;
  z[o] = z0;
  z[o + 1] = z1;
  lam[o] = sigmoidf_(l0 + bgr);
  lam[o + 1] = sigmoidf_(l1 + bgr);
}

// ---------------- K2: parallel linear scan over T (one wave per (b,r)) ----------------
__global__ __launch_bounds__(64) void k_scan(
    const float* __restrict__ z, const float* __restrict__ lam,
    const float* __restrict__ state, float* __restrict__ S,
    float* __restrict__ out_state) {
  int br = blockIdx.x;     // b*R + r   (128 total)
  int lane = threadIdx.x;  // 64 lanes, 32 timesteps each
  const float* zr = z + (size_t)br * T_ + lane * 32;
  const float* lr = lam + (size_t)br * T_ + lane * 32;
  float zb[32], lb[32];
#pragma unroll
  for (int i = 0; i < 32; i += 4) {
    *reinterpret_cast<float4*>(&zb[i]) = *reinterpret_cast<const float4*>(&zr[i]);
    *reinterpret_cast<float4*>(&lb[i]) = *reinterpret_cast<const float4*>(&lr[i]);
  }
  float A = 1.0f, Z = 0.0f;
#pragma unroll
  for (int i = 0; i < 32; i++) { Z = lb[i] * Z + zb[i]; A *= lb[i]; }
  for (int off = 1; off < 64; off <<= 1) {
    float Ap = __shfl_up(A, off);
    float Zp = __shfl_up(Z, off);
    if (lane >= off) { Z = A * Zp + Z; A = A * Ap; }
  }
  float s0 = state[br];
  float Ae = __shfl_up(A, 1);
  float Ze = __shfl_up(Z, 1);
  float s = (lane == 0) ? s0 : (Ae * s0 + Ze);
  float sb[32];
#pragma unroll
  for (int i = 0; i < 32; i++) { s = lb[i] * s + zb[i]; sb[i] = s; }
  float* Sr = S + (size_t)br * T_ + lane * 32;
#pragma unroll
  for (int i = 0; i < 32; i += 4)
    *reinterpret_cast<float4*>(&Sr[i]) = *reinterpret_cast<const float4*>(&sb[i]);
  if (lane == 63) out_state[br] = s;  // new_state
}

// ---------------- K_tilde: tilde = S @ V (bf16 out), 16 tokens/block, V staged in LDS ----------------
__global__ __launch_bounds__(256) void k_tilde(
    const float* __restrict__ S, const float* __restrict__ V,
    u32* __restrict__ tilg) {
  __shared__ float V_lds[R_ * P_];     // 64 KB
  __shared__ float Sl[TK_][R_];        // 2 KB

  int tid = threadIdx.x;
  int token0 = blockIdx.x * TK_;
  int b = token0 >> 11;
  int tbase = token0 & (T_ - 1);

  // stage V (fully) and the S tile
#pragma unroll
  for (int k = 0; k < 16; k++) {
    int vidx = k * 256 + tid;
    reinterpret_cast<float4*>(V_lds)[vidx] = reinterpret_cast<const float4*>(V)[vidx];
  }
#pragma unroll
  for (int k = 0; k < 2; k++) {
    int i = k * 256 + tid;
    int rr = i >> 4, tok = i & 15;
    Sl[tok][rr] = S[((size_t)(b * R_ + rr)) * T_ + tbase + tok];
  }
  __syncthreads();

  float til0[TK_], til1[TK_];
#pragma unroll
  for (int tok = 0; tok < TK_; tok++) { til0[tok] = 0; til1[tok] = 0; }
#pragma unroll 4
  for (int rr = 0; rr < R_; rr++) {
    float2 vv = reinterpret_cast<const float2*>(V_lds + rr * P_)[tid];
#pragma unroll
    for (int tok = 0; tok < TK_; tok++) {
      float s = Sl[tok][rr];
      til0[tok] += s * vv.x;
      til1[tok] += s * vv.y;
    }
  }
#pragma unroll
  for (int tok = 0; tok < TK_; tok++) {
    u32 pk = (u32)f2bfb(til0[tok]) | ((u32)f2bfb(til1[tok]) << 16);
    tilg[((size_t)(token0 + tok) * P_ >> 1) + tid] = pk;
  }
}

// ---------------- K3b: x_after = x + f*tilde*fo_s, rmsnorm2, MLP, out ----------------
__global__ __launch_bounds__(256) void k_phase3b(
    const float* __restrict__ x, const float* __restrict__ g2,
    const int* __restrict__ idx, const float* __restrict__ wg,
    const u32* __restrict__ ftg, const u32* __restrict__ tilg,
    const float* __restrict__ Wo_s, const float* __restrict__ Wp_m,
    const float* __restrict__ Wo_m, float* __restrict__ out) {
  __shared__ u16 h2[G_][D_];          // 16 KB
  __shared__ float red[G_][4];

  int tid = threadIdx.x;
  int token0 = blockIdx.x * G_;
  int p0 = 2 * tid, p1 = p0 + 1;

  // per-thread quant scalars for its two p's
  float sgn0 = (p0 < NE_) ? 1.0f : -1.0f;
  float sgn1 = (p1 < NE_) ? 1.0f : -1.0f;
  float fo_s0, fo_s1, fo_m0, fo_m1, wq_m0, wq_m1;
  {
    float4 a = *reinterpret_cast<const float4*>(Wo_s + p0 * ALPHA_);
    float4 c = *reinterpret_cast<const float4*>(Wo_s + p1 * ALPHA_);
    fo_s0 = sgn0 * (fabsf(a.x) + fabsf(a.y) + fabsf(a.z) + fabsf(a.w)) * (1.0f / ALPHA_);
    fo_s1 = sgn1 * (fabsf(c.x) + fabsf(c.y) + fabsf(c.z) + fabsf(c.w)) * (1.0f / ALPHA_);
    float4 e = *reinterpret_cast<const float4*>(Wo_m + p0 * ALPHA_);
    float4 g = *reinterpret_cast<const float4*>(Wo_m + p1 * ALPHA_);
    fo_m0 = sgn0 * (fabsf(e.x) + fabsf(e.y) + fabsf(e.z) + fabsf(e.w)) * (1.0f / ALPHA_);
    fo_m1 = sgn1 * (fabsf(g.x) + fabsf(g.y) + fabsf(g.z) + fabsf(g.w)) * (1.0f / ALPHA_);
    const float4* w0 = reinterpret_cast<const float4*>(Wp_m + p0 * K_);
    const float4* w1 = reinterpret_cast<const float4*>(Wp_m + p1 * K_);
    float a0 = 0, a1 = 0;
#pragma unroll
    for (int q = 0; q < 4; q++) {
      float4 v0 = w0[q], v1 = w1[q];
      a0 += fabsf(v0.x) + fabsf(v0.y) + fabsf(v0.z) + fabsf(v0.w);
      a1 += fabsf(v1.x) + fabsf(v1.y) + fabsf(v1.z) + fabsf(v1.w);
    }
    wq_m0 = sgn0 * a0 * (1.0f / K_);
    wq_m1 = sgn1 * a1 * (1.0f / K_);
  }
  float gv[8];
  {
    const float4* gp = reinterpret_cast<const float4*>(g2 + tid * 8);
    *reinterpret_cast<float4*>(&gv[0]) = gp[0];
    *reinterpret_cast<float4*>(&gv[4]) = gp[1];
  }

  // x_after + rmsnorm2
  float xa[G_][8];
#pragma unroll
  for (int tok = 0; tok < G_; tok++) {
    size_t trow = (size_t)(token0 + tok);
    const float4* xp = reinterpret_cast<const float4*>(x + trow * D_ + tid * 8);
    float xv[8];
    *reinterpret_cast<float4*>(&xv[0]) = xp[0];
    *reinterpret_cast<float4*>(&xv[4]) = xp[1];
    uint2 fp = *reinterpret_cast<const uint2*>(ftg + trow * P_ + p0);
    u32 tl = tilg[(trow * P_ >> 1) + tid];
    float f0 = bfb2f(fp.x & 0xffffu);
    float f1 = bfb2f(fp.y & 0xffffu);
    float val0 = f0 * bfb2f(tl & 0xffffu) * fo_s0;
    float val1 = f1 * bfb2f(tl >> 16) * fo_s1;
    float ss = 0;
#pragma unroll
    for (int a = 0; a < 4; a++) {
      float v0 = xv[a] + val0;
      float v1 = xv[4 + a] + val1;
      xa[tok][a] = v0;
      xa[tok][4 + a] = v1;
      ss += v0 * v0 + v1 * v1;
    }
#pragma unroll
    for (int off = 32; off; off >>= 1) ss += __shfl_down(ss, off);
    if ((tid & 63) == 0) red[tok][tid >> 6] = ss;
  }
  __syncthreads();
#pragma unroll
  for (int tok = 0; tok < G_; tok++) {
    float inv = rsqrtf((red[tok][0] + red[tok][1] + red[tok][2] + red[tok][3]) * (1.0f / D_) + EPS_);
    u16 tmp[8];
#pragma unroll
    for (int i = 0; i < 8; i++) tmp[i] = f2bfb(xa[tok][i] * inv * gv[i]);
    *reinterpret_cast<uint4*>(&h2[tok][tid * 8]) = *reinterpret_cast<const uint4*>(tmp);
  }
  __syncthreads();

  // MLP gather: weights for p0,p1 cached, reused across tokens
  union { int4 v[4]; int s[16]; } iu0, iu1;
  union { float4 v[4]; float s[16]; } wu0, wu1;
  {
    const int4* ip0 = reinterpret_cast<const int4*>(idx + p0 * K_);
    const int4* ip1 = reinterpret_cast<const int4*>(idx + p1 * K_);
    const float4* wp0 = reinterpret_cast<const float4*>(wg + p0 * K_);
    const float4* wp1 = reinterpret_cast<const float4*>(wg + p1 * K_);
#pragma unroll
    for (int q = 0; q < 4; q++) { iu0.v[q] = ip0[q]; iu1.v[q] = ip1[q]; wu0.v[q] = wp0[q]; wu1.v[q] = wp1[q]; }
  }

#pragma unroll
  for (int tok = 0; tok < G_; tok++) {
    float acc0 = 0, acc1 = 0;
#pragma unroll
    for (int k = 0; k < K_; k++) {
      acc0 += bfb2f(h2[tok][iu0.s[k]]) * wu0.s[k];
      acc1 += bfb2f(h2[tok][iu1.s[k]]) * wu1.s[k];
    }
    float u0 = wq_m0 * acc0, u1 = wq_m1 * acc1;
    float f0 = sigmoidf_(u0), f1 = sigmoidf_(u1);
    float val0 = f0 * u0 * fo_m0, val1 = f1 * u1 * fo_m1;
    float ov[8];
#pragma unroll
    for (int a = 0; a < 4; a++) {
      ov[a] = xa[tok][a] + val0;
      ov[4 + a] = xa[tok][4 + a] + val1;
    }
    float4* op = reinterpret_cast<float4*>(out + (size_t)(token0 + tok) * D_ + tid * 8);
    op[0] = *reinterpret_cast<const float4*>(&ov[0]);
    op[1] = *reinterpret_cast<const float4*>(&ov[4]);
  }
}

// ---------------- host ----------------
extern "C" void kernel_launch(void* const* d_in, const int* in_sizes, int n_in,
                              void* d_out, int out_size, void* d_ws, size_t ws_size,
                              hipStream_t stream) {
  const float* x     = (const float*)d_in[0];
  const float* state = (const float*)d_in[1];
  const float* g1    = (const float*)d_in[2];
  const float* g2    = (const float*)d_in[3];
  const int*   idx_s = (const int*)d_in[4];
  const float* wg_s  = (const float*)d_in[5];
  const int*   idx_m = (const int*)d_in[6];
  const float* wg_m  = (const float*)d_in[7];
  const float* Wp_s  = (const float*)d_in[8];
  const float* Wo_s  = (const float*)d_in[9];
  const float* Wp_m  = (const float*)d_in[10];
  const float* Wo_m  = (const float*)d_in[11];
  const float* U     = (const float*)d_in[12];
  const float* V     = (const float*)d_in[13];
  const float* Wgt   = (const float*)d_in[14];
  const float* bg    = (const float*)d_in[15];
  float* out = (float*)d_out;

  char* ws = (char*)d_ws;
  u32* ftg  = (u32*)ws;                                                // B*T*P u32 = 16 MB
  size_t off = (size_t)B_ * T_ * P_ * 4;
  float* z   = (float*)(ws + off); off += (size_t)B_ * R_ * T_ * 4;    // 1 MB
  float* lam = (float*)(ws + off); off += (size_t)B_ * R_ * T_ * 4;    // 1 MB
  float* S   = (float*)(ws + off); off += (size_t)B_ * R_ * T_ * 4;    // 1 MB
  u32* tilg  = (u32*)(ws + off);                                       // B*T*P/2 u32 = 8 MB

  hipLaunchKernelGGL(k_phase1a, dim3(B_ * T_ / G_), dim3(256), 0, stream,
                     x, g1, idx_s, wg_s, Wp_s, ftg);
  hipLaunchKernelGGL(k_zlam, dim3(B_ * T_ / TK_), dim3(256), 0, stream,
                     ftg, U, Wgt, bg, z, lam);
  hipLaunchKernelGGL(k_scan, dim3(B_ * R_), dim3(64), 0, stream,
                     z, lam, state, S, out + (size_t)B_ * T_ * D_);
  hipLaunchKernelGGL(k_tilde, dim3(B_ * T_ / TK_), dim3(256), 0, stream,
                     S, V, tilg);
  hipLaunchKernelGGL(k_phase3b, dim3(B_ * T_ / G_), dim3(256), 0, stream,
                     x, g2, idx_m, wg_m, ftg, tilg, Wo_s, Wp_m, Wo_m, out);
}